// Round 8
// baseline (2256.874 us; speedup 1.0000x reference)
//
#include <hip/hip_runtime.h>
#include <cstdint>

typedef unsigned short u16;
typedef unsigned int   u32;

__device__ __forceinline__ float bf2f(u16 u){ return __uint_as_float(((u32)u) << 16); }

// Decide if a float tensor is stored as bf16 (u16) or fp32.
__device__ __forceinline__ int detect_bf16(const void* p){
    const u16* h = (const u16*)p;
    int hits = 0;
    for (int i = 0; i < 64; ++i){
        const int e = (h[2 * i] >> 7) & 0xFF;
        hits += (e >= 110 && e <= 140) ? 1 : 0;
    }
    return hits >= 40;
}

// int64 (torch-long) vs int32 index tensor: int64 => odd 32-bit words ~all zero.
__device__ __forceinline__ int detect_i64(const int* p){
    int z = 0;
    for (int i = 0; i < 48; ++i) z += (p[2 * i + 1] == 0) ? 1 : 0;
    return z >= 40;
}

__device__ __forceinline__ float ldf(const void* p, size_t i, int isbf){
    return isbf ? bf2f(((const u16*)p)[i]) : ((const float*)p)[i];
}

// Literal transcription of the reference, one block per query, fp32 throughout.
// threads = 128, thread t owns channel/index t of each 128-vector.
// OUTPUT IS FP32 (reference output dtype) — this is the round-8 fix.
__global__ __launch_bounds__(128) void k_simple(const void* __restrict__ qf_,
                                                const void* __restrict__ feat_,
                                                const void* __restrict__ proj_,
                                                const void* __restrict__ qw_,
                                                const void* __restrict__ qb_,
                                                const void* __restrict__ kw_,
                                                const void* __restrict__ kb_,
                                                const void* __restrict__ vw_,
                                                const void* __restrict__ vb_,
                                                float* __restrict__ out){
    __shared__ float qfs[128];
    __shared__ float qs[128];
    __shared__ float ts[128];
    __shared__ float gs[128];
    __shared__ float ss4[27][4];
    __shared__ float aa[27];
    __shared__ float kbd[1];

    const int t = threadIdx.x;
    const int q = blockIdx.x;
    const int b = q >> 13;

    const int is_qf = detect_bf16(qf_);
    const int is_ft = detect_bf16(feat_);
    const int is_qw = detect_bf16(qw_);
    const int is_qb = detect_bf16(qb_);
    const int is_kw = detect_bf16(kw_);
    const int is_kb = detect_bf16(kb_);
    const int is_vw = detect_bf16(vw_);
    const int is_vb = detect_bf16(vb_);
    const int p64   = detect_i64((const int*)proj_);

    qfs[t] = ldf(qf_, (size_t)q * 128 + t, is_qf);
    __syncthreads();

    // q_d = sum_e qw[d][e] * qf[e] + qb[d]
    {
        float acc = ldf(qb_, t, is_qb);
        for (int e = 0; e < 128; ++e)
            acc += ldf(qw_, (size_t)t * 128 + e, is_qw) * qfs[e];
        qs[t] = acc;
    }
    __syncthreads();

    // t_c = sum_d kw[d][c] * q_d   (exact fold of q . (k_w f))
    {
        float acc = 0.f;
        for (int d = 0; d < 128; ++d)
            acc += ldf(kw_, (size_t)d * 128 + t, is_kw) * qs[d];
        ts[t] = acc;
    }
    if (t == 0){
        float kd = 0.f;
        for (int d = 0; d < 128; ++d) kd += ldf(kb_, d, is_kb) * qs[d];
        kbd[0] = kd;
    }
    __syncthreads();

    int pz, py, px;
    if (p64){
        pz = ((const int*)proj_)[(size_t)(q * 3 + 0) * 2];
        py = ((const int*)proj_)[(size_t)(q * 3 + 1) * 2];
        px = ((const int*)proj_)[(size_t)(q * 3 + 2) * 2];
    } else {
        pz = ((const int*)proj_)[q * 3 + 0];
        py = ((const int*)proj_)[q * 3 + 1];
        px = ((const int*)proj_)[q * 3 + 2];
    }
    pz = min(max(pz, 0), 47); py = min(max(py, 0), 47); px = min(max(px, 0), 47);

    // s_k = t . f_k  (+ q.k_b)
    if (t < 108){
        const int k = t >> 2, part = t & 3;
        const int dz = k / 9, dy = (k / 3) % 3, dx = k % 3;
        const int zz = min(max(pz - 1 + dz, 0), 47);
        const int yy = min(max(py - 1 + dy, 0), 47);
        const int xx = min(max(px - 1 + dx, 0), 47);
        const size_t sp = (size_t)zz * 2304 + yy * 48 + xx;
        float s = 0.f;
        for (int c = part * 32; c < part * 32 + 32; ++c)
            s += ts[c] * ldf(feat_, ((size_t)b * 128 + c) * 110592 + sp, is_ft);
        ss4[k][part] = s;
    }
    __syncthreads();

    if (t == 0){
        float sc[27];
        float mx = -1e30f;
        for (int k = 0; k < 27; ++k){
            sc[k] = ss4[k][0] + ss4[k][1] + ss4[k][2] + ss4[k][3] + kbd[0];
            mx = fmaxf(mx, sc[k]);
        }
        float Z = 0.f;
        for (int k = 0; k < 27; ++k){ sc[k] = expf(sc[k] - mx); Z += sc[k]; }
        const float inv = 1.0f / Z;
        for (int k = 0; k < 27; ++k) aa[k] = sc[k] * inv;
    }
    __syncthreads();

    // g_c = sum_k a_k * f_kc
    {
        float g = 0.f;
        const size_t cb = ((size_t)b * 128 + t) * 110592;
        for (int k = 0; k < 27; ++k){
            const int dz = k / 9, dy = (k / 3) % 3, dx = k % 3;
            const int zz = min(max(pz - 1 + dz, 0), 47);
            const int yy = min(max(py - 1 + dy, 0), 47);
            const int xx = min(max(px - 1 + dx, 0), 47);
            g += aa[k] * ldf(feat_, cb + (size_t)zz * 2304 + yy * 48 + xx, is_ft);
        }
        gs[t] = g;
    }
    __syncthreads();

    // out_d = qf_d + vb_d + sum_c vw[d][c] * g_c   — stored as FP32
    {
        float o = qfs[t] + ldf(vb_, t, is_vb);
        for (int c = 0; c < 128; ++c)
            o += ldf(vw_, (size_t)t * 128 + c, is_vw) * gs[c];
        out[(size_t)q * 128 + t] = o;
    }
}

extern "C" void kernel_launch(void* const* d_in, const int* in_sizes, int n_in,
                              void* d_out, int out_size, void* d_ws, size_t ws_size,
                              hipStream_t stream) {
    const void* qfeat = d_in[0];   // (2,8192,128)   bf16 (detected)
    const void* feat  = d_in[1];   // (2,128,48,48,48) bf16 (detected)
    const void* proj  = d_in[2];   // (2,8192,3) int32/int64 (detected)
    // d_in[3] hr_coord: unused by the reference math
    const void* qw = d_in[4];
    const void* qb = d_in[5];
    const void* kw = d_in[6];
    const void* kb = d_in[7];
    const void* vw = d_in[8];
    const void* vb = d_in[9];
    float* out = (float*)d_out;    // reference output dtype = float32

    hipLaunchKernelGGL(k_simple, dim3(16384), dim3(128), 0, stream,
                       qfeat, feat, proj, qw, qb, kw, kb, vw, vb, out);
}

// Round 9
// 368.886 us; speedup vs baseline: 6.1181x; 6.1181x over previous
//
#include <hip/hip_runtime.h>
#include <cstdint>

typedef unsigned short u16;
typedef unsigned int   u32;

__device__ __forceinline__ float bf2f(u16 u){ return __uint_as_float(((u32)u) << 16); }
__device__ __forceinline__ float bflo(u32 u){ return __uint_as_float(u << 16); }
__device__ __forceinline__ float bfhi(u32 u){ return __uint_as_float(u & 0xffff0000u); }
__device__ __forceinline__ u16 f2bf(float f){
    u32 x = __float_as_uint(f);
    u32 r = x + 0x7fffu + ((x >> 16) & 1u);
    return (u16)(r >> 16);
}
__device__ __forceinline__ int detect_bf16(const void* p){
    const u16* h = (const u16*)p;
    int hits = 0;
    for (int i = 0; i < 64; ++i){
        const int e = (h[2 * i] >> 7) & 0xFF;
        hits += (e >= 110 && e <= 140) ? 1 : 0;
    }
    return hits >= 40;
}
__device__ __forceinline__ int detect_i64(const int* p){
    int z = 0;
    for (int i = 0; i < 48; ++i) z += (p[2 * i + 1] == 0) ? 1 : 0;
    return z >= 40;
}
__device__ __forceinline__ float ldf(const void* p, size_t i, int isbf){
    return isbf ? bf2f(((const u16*)p)[i]) : ((const float*)p)[i];
}
__device__ __forceinline__ void read_proj(const int* proj, int q, int p64,
                                          int& pz, int& py, int& px){
    if (p64){
        pz = proj[(size_t)(q * 3 + 0) * 2];
        py = proj[(size_t)(q * 3 + 1) * 2];
        px = proj[(size_t)(q * 3 + 2) * 2];
    } else {
        pz = proj[q * 3 + 0]; py = proj[q * 3 + 1]; px = proj[q * 3 + 2];
    }
    pz = min(max(pz, 0), 47); py = min(max(py, 0), 47); px = min(max(px, 0), 47);
}

// ---------------- prep: M[e][c] = sum_d qw[d][e]*kw[d][c];  bias[c] = sum_d kw[d][c]*qb[d]
__global__ __launch_bounds__(128) void k_prep(const void* __restrict__ qw_,
                                              const void* __restrict__ qb_,
                                              const void* __restrict__ kw_,
                                              float* __restrict__ M, float* __restrict__ bias){
    const int e = blockIdx.x, c = threadIdx.x;
    const int is_qw = detect_bf16(qw_), is_kw = detect_bf16(kw_), is_qb = detect_bf16(qb_);
    float acc = 0.f;
    for (int d = 0; d < 128; ++d)
        acc += ldf(kw_, (size_t)d * 128 + c, is_kw) * ldf(qw_, (size_t)d * 128 + e, is_qw);
    M[e * 128 + c] = acc;
    if (e == 0){
        float ab = 0.f;
        for (int d = 0; d < 128; ++d)
            ab += ldf(kw_, (size_t)d * 128 + c, is_kw) * ldf(qb_, d, is_qb);
        bias[c] = ab;
    }
}

// ---------------- prep: W2[c][d] = vw[d][c]  (fp32)
__global__ __launch_bounds__(256) void k_w2(const void* __restrict__ vw_, float* __restrict__ W2){
    const int i = blockIdx.x * 256 + threadIdx.x;   // 16384
    const int c = i >> 7, d = i & 127;
    const int is_vw = detect_bf16(vw_);
    W2[c * 128 + d] = ldf(vw_, (size_t)d * 128 + c, is_vw);
}

// ---------------- pad + transpose (B,C,48,48,48) -> (B,50,50,50,C) bf16
__global__ __launch_bounds__(256) void k_padT(const void* __restrict__ feat_,
                                              u16* __restrict__ featT){
    __shared__ u16 sh[128 * 50];
    const int bi = blockIdx.x;              // b*2500 + z'*50 + y'
    const int b  = bi / 2500;
    const int r  = bi - b * 2500;
    const int z  = r / 50;
    const int y  = r - z * 50;
    const int zs = min(max(z - 1, 0), 47);
    const int ys = min(max(y - 1, 0), 47);
    const int isbf = detect_bf16(feat_);
    if (isbf){
        const u16* feat = (const u16*)feat_;
        for (int i = threadIdx.x; i < 128 * 12; i += 256){
            const int c  = i / 12;
            const int xq = i - c * 12;
            const size_t src = (((size_t)(b * 128 + c) * 48 + zs) * 48 + ys) * 48 + xq * 4;
            const uint2 v = *reinterpret_cast<const uint2*>(feat + src);
            u32* p = reinterpret_cast<u32*>(&sh[c * 50 + xq * 4]);
            p[0] = v.x; p[1] = v.y;
        }
    } else {
        const float* feat = (const float*)feat_;
        for (int i = threadIdx.x; i < 128 * 12; i += 256){
            const int c  = i / 12;
            const int xq = i - c * 12;
            const size_t src = (((size_t)(b * 128 + c) * 48 + zs) * 48 + ys) * 48 + xq * 4;
            const float4 v = *reinterpret_cast<const float4*>(feat + src);
            u32* p = reinterpret_cast<u32*>(&sh[c * 50 + xq * 4]);
            p[0] = (u32)f2bf(v.x) | ((u32)f2bf(v.y) << 16);
            p[1] = (u32)f2bf(v.z) | ((u32)f2bf(v.w) << 16);
        }
    }
    __syncthreads();
    const size_t obase = (size_t)bi * 6400;
    for (int i = threadIdx.x; i < 50 * 64; i += 256){
        const int xp = i >> 6;
        const int cp = i & 63;
        const int xs = min(max(xp - 1, 0), 47);
        const u32 lo = sh[(2 * cp    ) * 50 + xs];
        const u32 hi = sh[(2 * cp + 1) * 50 + xs];
        *reinterpret_cast<u32*>(featT + obase + xp * 128 + 2 * cp) = lo | (hi << 16);
    }
}

// ---------------- qk_all[q][c] = sum_e qf[q][e]*M[e][c] + bias[c]
// 128 blocks x 256 thr; block = 128 queries. M (64 KB fp32) in LDS.
// Thread: 32-lane group tg=t>>5 owns query stream; lane32 owns c-quad 4*(t&31).
__global__ __launch_bounds__(256) void k_qk(const void* __restrict__ qf_,
                                            const float* __restrict__ M,
                                            const float* __restrict__ bias,
                                            float* __restrict__ qk_all){
    __shared__ float Msh[128 * 128];
    const int t = threadIdx.x;
    const int is_qf = detect_bf16(qf_);
    {
        const float4* Mg4 = reinterpret_cast<const float4*>(M);
        float4* Ms4 = reinterpret_cast<float4*>(Msh);
        for (int i = t; i < 4096; i += 256) Ms4[i] = Mg4[i];
    }
    __syncthreads();
    const int tg = t >> 5, lane32 = t & 31;
    const int cq = lane32 * 4;
    const float4 b4 = *reinterpret_cast<const float4*>(bias + cq);
    const int qbase = blockIdx.x * 128;
    for (int qi = tg; qi < 128; qi += 16){
        const int qa = qbase + qi, qb2 = qbase + qi + 8;
        float qvA[4], qvB[4];
        if (is_qf){
            const ushort4 a = *reinterpret_cast<const ushort4*>((const u16*)qf_ + (size_t)qa * 128 + lane32 * 4);
            const ushort4 b = *reinterpret_cast<const ushort4*>((const u16*)qf_ + (size_t)qb2 * 128 + lane32 * 4);
            qvA[0]=bf2f(a.x); qvA[1]=bf2f(a.y); qvA[2]=bf2f(a.z); qvA[3]=bf2f(a.w);
            qvB[0]=bf2f(b.x); qvB[1]=bf2f(b.y); qvB[2]=bf2f(b.z); qvB[3]=bf2f(b.w);
        } else {
            const float4 a = *reinterpret_cast<const float4*>((const float*)qf_ + (size_t)qa * 128 + lane32 * 4);
            const float4 b = *reinterpret_cast<const float4*>((const float*)qf_ + (size_t)qb2 * 128 + lane32 * 4);
            qvA[0]=a.x; qvA[1]=a.y; qvA[2]=a.z; qvA[3]=a.w;
            qvB[0]=b.x; qvB[1]=b.y; qvB[2]=b.z; qvB[3]=b.w;
        }
        float4 accA = b4, accB = b4;
#pragma unroll 4
        for (int es = 0; es < 32; ++es){
#pragma unroll
            for (int j = 0; j < 4; ++j){
                const int e = es * 4 + j;
                const float4 m = *reinterpret_cast<const float4*>(&Msh[e * 128 + cq]);
                const float qeA = __shfl(qvA[j], es, 32);
                const float qeB = __shfl(qvB[j], es, 32);
                accA.x += qeA * m.x; accA.y += qeA * m.y; accA.z += qeA * m.z; accA.w += qeA * m.w;
                accB.x += qeB * m.x; accB.y += qeB * m.y; accB.z += qeB * m.z; accB.w += qeB * m.w;
            }
        }
        *reinterpret_cast<float4*>(qk_all + (size_t)qa  * 128 + cq) = accA;
        *reinterpret_cast<float4*>(qk_all + (size_t)qb2 * 128 + cq) = accB;
    }
}

// ---------------- attention gather from featT; g (fp32) to ws. 1 wave/query.
__global__ __launch_bounds__(256) void k_attn_feat(const u16* __restrict__ featT,
                                                   const float* __restrict__ qk_all,
                                                   const int* __restrict__ proj,
                                                   float* __restrict__ g){
    const int lane = threadIdx.x & 63;
    const int q = blockIdx.x * 4 + (threadIdx.x >> 6);
    const int kg = lane >> 4, cl = lane & 15;
    const int b = q >> 13;
    const int p64 = detect_i64(proj);
    int pz, py, px; read_proj(proj, q, p64, pz, py, px);
    const float4* qp4 = reinterpret_cast<const float4*>(qk_all + (size_t)q * 128 + cl * 8);
    const float4 qA = qp4[0], qB = qp4[1];
    const u16* base = featT + (size_t)b * 16000000
                      + ((size_t)pz * 2500 + py * 50 + px) * 128 + cl * 8;
    uint4 fr[7];
    float sc[7];
#pragma unroll
    for (int s = 0; s < 7; ++s){
        const int k = s * 4 + kg;
        uint4 v = make_uint4(0u, 0u, 0u, 0u);
        if (k < 27){
            const int dz = k / 9, r9 = k - dz * 9, dy = r9 / 3, dx = r9 - dy * 3;
            v = *reinterpret_cast<const uint4*>(base + (dz * 2500 + dy * 50 + dx) * 128);
        }
        fr[s] = v;
        float t = qA.x * bflo(v.x) + qA.y * bfhi(v.x)
                + qA.z * bflo(v.y) + qA.w * bfhi(v.y)
                + qB.x * bflo(v.z) + qB.y * bfhi(v.z)
                + qB.z * bflo(v.w) + qB.w * bfhi(v.w);
        t += __shfl_xor(t, 1, 64);
        t += __shfl_xor(t, 2, 64);
        t += __shfl_xor(t, 4, 64);
        t += __shfl_xor(t, 8, 64);
        sc[s] = (k < 27) ? t : -1e30f;
    }
    float mx = sc[0];
#pragma unroll
    for (int s = 1; s < 7; ++s) mx = fmaxf(mx, sc[s]);
    mx = fmaxf(mx, __shfl_xor(mx, 16, 64));
    mx = fmaxf(mx, __shfl_xor(mx, 32, 64));
    float e[7], Z = 0.f;
#pragma unroll
    for (int s = 0; s < 7; ++s){ e[s] = __expf(sc[s] - mx); Z += e[s]; }
    Z += __shfl_xor(Z, 16, 64);
    Z += __shfl_xor(Z, 32, 64);
    const float inv = 1.0f / Z;
    float w[8];
#pragma unroll
    for (int i = 0; i < 8; ++i) w[i] = 0.f;
#pragma unroll
    for (int s = 0; s < 7; ++s){
        const float a = e[s] * inv;
        w[0] += a * bflo(fr[s].x); w[1] += a * bfhi(fr[s].x);
        w[2] += a * bflo(fr[s].y); w[3] += a * bfhi(fr[s].y);
        w[4] += a * bflo(fr[s].z); w[5] += a * bfhi(fr[s].z);
        w[6] += a * bflo(fr[s].w); w[7] += a * bfhi(fr[s].w);
    }
#pragma unroll
    for (int i = 0; i < 8; ++i){
        w[i] += __shfl_xor(w[i], 16, 64);
        w[i] += __shfl_xor(w[i], 32, 64);
    }
    if (kg == 0){
        float4 lo4; lo4.x = w[0]; lo4.y = w[1]; lo4.z = w[2]; lo4.w = w[3];
        float4 hi4; hi4.x = w[4]; hi4.y = w[5]; hi4.z = w[6]; hi4.w = w[7];
        float4* o = reinterpret_cast<float4*>(g + (size_t)q * 128 + cl * 8);
        o[0] = lo4; o[1] = hi4;
    }
}

// ---------------- tier-2: gather directly from feat (B,C,48^3)
__global__ __launch_bounds__(256) void k_attn_direct(const void* __restrict__ feat_,
                                                     const float* __restrict__ qk_all,
                                                     const int* __restrict__ proj,
                                                     float* __restrict__ g){
    const int lane = threadIdx.x & 63;
    const int q = blockIdx.x * 4 + (threadIdx.x >> 6);
    const int kg = lane >> 4, cl = lane & 15;
    const int b = q >> 13;
    const int isbf = detect_bf16(feat_);
    const int p64 = detect_i64(proj);
    int pz, py, px; read_proj(proj, q, p64, pz, py, px);
    const float* qk = qk_all + (size_t)q * 128 + cl * 8;
    float qv[8];
#pragma unroll
    for (int i = 0; i < 8; ++i) qv[i] = qk[i];
    const size_t cbase = ((size_t)b * 128 + cl * 8) * 110592;
    float f[7][8];
    float sc[7];
#pragma unroll
    for (int s = 0; s < 7; ++s){
        const int k = s * 4 + kg;
#pragma unroll
        for (int i = 0; i < 8; ++i) f[s][i] = 0.f;
        if (k < 27){
            const int dz = k / 9, r9 = k - dz * 9, dy = r9 / 3, dx = r9 - dy * 3;
            const int zz = min(max(pz - 1 + dz, 0), 47);
            const int yy = min(max(py - 1 + dy, 0), 47);
            const int xx = min(max(px - 1 + dx, 0), 47);
            const size_t off = (size_t)zz * 2304 + yy * 48 + xx;
#pragma unroll
            for (int i = 0; i < 8; ++i) f[s][i] = ldf(feat_, cbase + (size_t)i * 110592 + off, isbf);
        }
        float t = 0.f;
#pragma unroll
        for (int i = 0; i < 8; ++i) t += qv[i] * f[s][i];
        t += __shfl_xor(t, 1, 64);
        t += __shfl_xor(t, 2, 64);
        t += __shfl_xor(t, 4, 64);
        t += __shfl_xor(t, 8, 64);
        sc[s] = (k < 27) ? t : -1e30f;
    }
    float mx = sc[0];
#pragma unroll
    for (int s = 1; s < 7; ++s) mx = fmaxf(mx, sc[s]);
    mx = fmaxf(mx, __shfl_xor(mx, 16, 64));
    mx = fmaxf(mx, __shfl_xor(mx, 32, 64));
    float e[7], Z = 0.f;
#pragma unroll
    for (int s = 0; s < 7; ++s){ e[s] = __expf(sc[s] - mx); Z += e[s]; }
    Z += __shfl_xor(Z, 16, 64);
    Z += __shfl_xor(Z, 32, 64);
    const float inv = 1.0f / Z;
    float w[8];
#pragma unroll
    for (int i = 0; i < 8; ++i) w[i] = 0.f;
#pragma unroll
    for (int s = 0; s < 7; ++s){
        const float a = e[s] * inv;
#pragma unroll
        for (int i = 0; i < 8; ++i) w[i] += a * f[s][i];
    }
#pragma unroll
    for (int i = 0; i < 8; ++i){
        w[i] += __shfl_xor(w[i], 16, 64);
        w[i] += __shfl_xor(w[i], 32, 64);
    }
    if (kg == 0){
        float4 lo4; lo4.x = w[0]; lo4.y = w[1]; lo4.z = w[2]; lo4.w = w[3];
        float4 hi4; hi4.x = w[4]; hi4.y = w[5]; hi4.z = w[6]; hi4.w = w[7];
        float4* o = reinterpret_cast<float4*>(g + (size_t)q * 128 + cl * 8);
        o[0] = lo4; o[1] = hi4;
    }
}

// ---------------- out[q][d] = qf[q][d] + vb[d] + sum_c g[q][c]*W2[c][d]   (fp32 out)
__global__ __launch_bounds__(256) void k_out(const float* __restrict__ g,
                                             const float* __restrict__ W2,
                                             const void* __restrict__ qf_,
                                             const void* __restrict__ vb_,
                                             float* __restrict__ out){
    __shared__ float Wsh[128 * 128];
    const int t = threadIdx.x;
    const int is_qf = detect_bf16(qf_);
    const int is_vb = detect_bf16(vb_);
    {
        const float4* Wg4 = reinterpret_cast<const float4*>(W2);
        float4* Ws4 = reinterpret_cast<float4*>(Wsh);
        for (int i = t; i < 4096; i += 256) Ws4[i] = Wg4[i];
    }
    __syncthreads();
    const int tg = t >> 5, lane32 = t & 31;
    const int dq = lane32 * 4;
    float4 vb4;
    if (is_vb){
        const ushort4 v = *reinterpret_cast<const ushort4*>((const u16*)vb_ + dq);
        vb4.x = bf2f(v.x); vb4.y = bf2f(v.y); vb4.z = bf2f(v.z); vb4.w = bf2f(v.w);
    } else {
        vb4 = *reinterpret_cast<const float4*>((const float*)vb_ + dq);
    }
    const int qbase = blockIdx.x * 128;
    for (int qi = tg; qi < 128; qi += 16){
        const int qa = qbase + qi, qb2 = qbase + qi + 8;
        const float4 gA = *reinterpret_cast<const float4*>(g + (size_t)qa  * 128 + lane32 * 4);
        const float4 gB = *reinterpret_cast<const float4*>(g + (size_t)qb2 * 128 + lane32 * 4);
        const float gvA[4] = {gA.x, gA.y, gA.z, gA.w};
        const float gvB[4] = {gB.x, gB.y, gB.z, gB.w};
        float4 accA = vb4, accB = vb4;
#pragma unroll 4
        for (int cs = 0; cs < 32; ++cs){
#pragma unroll
            for (int j = 0; j < 4; ++j){
                const int c = cs * 4 + j;
                const float4 m = *reinterpret_cast<const float4*>(&Wsh[c * 128 + dq]);
                const float geA = __shfl(gvA[j], cs, 32);
                const float geB = __shfl(gvB[j], cs, 32);
                accA.x += geA * m.x; accA.y += geA * m.y; accA.z += geA * m.z; accA.w += geA * m.w;
                accB.x += geB * m.x; accB.y += geB * m.y; accB.z += geB * m.z; accB.w += geB * m.w;
            }
        }
        float4 rA, rB;
        if (is_qf){
            const ushort4 a = *reinterpret_cast<const ushort4*>((const u16*)qf_ + (size_t)qa * 128 + dq);
            const ushort4 b = *reinterpret_cast<const ushort4*>((const u16*)qf_ + (size_t)qb2 * 128 + dq);
            rA.x = bf2f(a.x); rA.y = bf2f(a.y); rA.z = bf2f(a.z); rA.w = bf2f(a.w);
            rB.x = bf2f(b.x); rB.y = bf2f(b.y); rB.z = bf2f(b.z); rB.w = bf2f(b.w);
        } else {
            rA = *reinterpret_cast<const float4*>((const float*)qf_ + (size_t)qa * 128 + dq);
            rB = *reinterpret_cast<const float4*>((const float*)qf_ + (size_t)qb2 * 128 + dq);
        }
        accA.x += rA.x; accA.y += rA.y; accA.z += rA.z; accA.w += rA.w;
        accB.x += rB.x; accB.y += rB.y; accB.z += rB.z; accB.w += rB.w;
        *reinterpret_cast<float4*>(out + (size_t)qa  * 128 + dq) = accA;
        *reinterpret_cast<float4*>(out + (size_t)qb2 * 128 + dq) = accB;
    }
}

// ---------------- tier-3 fallback: the round-8 passing literal kernel
__global__ __launch_bounds__(128) void k_simple(const void* __restrict__ qf_,
                                                const void* __restrict__ feat_,
                                                const void* __restrict__ proj_,
                                                const void* __restrict__ qw_,
                                                const void* __restrict__ qb_,
                                                const void* __restrict__ kw_,
                                                const void* __restrict__ kb_,
                                                const void* __restrict__ vw_,
                                                const void* __restrict__ vb_,
                                                float* __restrict__ out){
    __shared__ float qfs[128];
    __shared__ float qs[128];
    __shared__ float ts[128];
    __shared__ float gs[128];
    __shared__ float ss4[27][4];
    __shared__ float aa[27];
    __shared__ float kbd[1];
    const int t = threadIdx.x;
    const int q = blockIdx.x;
    const int b = q >> 13;
    const int is_qf = detect_bf16(qf_);
    const int is_ft = detect_bf16(feat_);
    const int is_qw = detect_bf16(qw_);
    const int is_qb = detect_bf16(qb_);
    const int is_kw = detect_bf16(kw_);
    const int is_kb = detect_bf16(kb_);
    const int is_vw = detect_bf16(vw_);
    const int is_vb = detect_bf16(vb_);
    const int p64   = detect_i64((const int*)proj_);
    qfs[t] = ldf(qf_, (size_t)q * 128 + t, is_qf);
    __syncthreads();
    {
        float acc = ldf(qb_, t, is_qb);
        for (int e = 0; e < 128; ++e)
            acc += ldf(qw_, (size_t)t * 128 + e, is_qw) * qfs[e];
        qs[t] = acc;
    }
    __syncthreads();
    {
        float acc = 0.f;
        for (int d = 0; d < 128; ++d)
            acc += ldf(kw_, (size_t)d * 128 + t, is_kw) * qs[d];
        ts[t] = acc;
    }
    if (t == 0){
        float kd = 0.f;
        for (int d = 0; d < 128; ++d) kd += ldf(kb_, d, is_kb) * qs[d];
        kbd[0] = kd;
    }
    __syncthreads();
    int pz, py, px; read_proj((const int*)proj_, q, p64, pz, py, px);
    if (t < 108){
        const int k = t >> 2, part = t & 3;
        const int dz = k / 9, dy = (k / 3) % 3, dx = k % 3;
        const int zz = min(max(pz - 1 + dz, 0), 47);
        const int yy = min(max(py - 1 + dy, 0), 47);
        const int xx = min(max(px - 1 + dx, 0), 47);
        const size_t sp = (size_t)zz * 2304 + yy * 48 + xx;
        float s = 0.f;
        for (int c = part * 32; c < part * 32 + 32; ++c)
            s += ts[c] * ldf(feat_, ((size_t)b * 128 + c) * 110592 + sp, is_ft);
        ss4[k][part] = s;
    }
    __syncthreads();
    if (t == 0){
        float sc[27];
        float mx = -1e30f;
        for (int k = 0; k < 27; ++k){
            sc[k] = ss4[k][0] + ss4[k][1] + ss4[k][2] + ss4[k][3] + kbd[0];
            mx = fmaxf(mx, sc[k]);
        }
        float Z = 0.f;
        for (int k = 0; k < 27; ++k){ sc[k] = expf(sc[k] - mx); Z += sc[k]; }
        const float inv = 1.0f / Z;
        for (int k = 0; k < 27; ++k) aa[k] = sc[k] * inv;
    }
    __syncthreads();
    {
        float g = 0.f;
        const size_t cb = ((size_t)b * 128 + t) * 110592;
        for (int k = 0; k < 27; ++k){
            const int dz = k / 9, dy = (k / 3) % 3, dx = k % 3;
            const int zz = min(max(pz - 1 + dz, 0), 47);
            const int yy = min(max(py - 1 + dy, 0), 47);
            const int xx = min(max(px - 1 + dx, 0), 47);
            g += aa[k] * ldf(feat_, cb + (size_t)zz * 2304 + yy * 48 + xx, is_ft);
        }
        gs[t] = g;
    }
    __syncthreads();
    {
        float o = qfs[t] + ldf(vb_, t, is_vb);
        for (int c = 0; c < 128; ++c)
            o += ldf(vw_, (size_t)t * 128 + c, is_vw) * gs[c];
        out[(size_t)q * 128 + t] = o;
    }
}

extern "C" void kernel_launch(void* const* d_in, const int* in_sizes, int n_in,
                              void* d_out, int out_size, void* d_ws, size_t ws_size,
                              hipStream_t stream) {
    const void* qfeat = d_in[0];
    const void* feat  = d_in[1];
    const int*  proj  = (const int*)d_in[2];
    const void* qw = d_in[4];
    const void* qb = d_in[5];
    const void* kw = d_in[6];
    const void* kb = d_in[7];
    const void* vw = d_in[8];
    const void* vb = d_in[9];
    float* out = (float*)d_out;

    // ws layout
    char* wsb = (char*)d_ws;
    float* M      = (float*)(wsb);                //     65,536 B
    float* bias   = (float*)(wsb + 65536);        //        512 B
    float* W2     = (float*)(wsb + 66048);        //     65,536 B
    float* qk_all = (float*)(wsb + 131584);       //  8,388,608 B
    float* g      = (float*)(wsb + 8520192);      //  8,388,608 B
    u16*   featT  = (u16*)  (wsb + 16908800);     // 64,000,000 B -> 80,908,800 total

    const int tier = (ws_size >= (size_t)80908800) ? 1
                   : (ws_size >= (size_t)16908800) ? 2 : 3;

    if (tier == 3){
        hipLaunchKernelGGL(k_simple, dim3(16384), dim3(128), 0, stream,
                           qfeat, feat, proj, qw, qb, kw, kb, vw, vb, out);
        return;
    }
    hipLaunchKernelGGL(k_prep, dim3(128), dim3(128), 0, stream, qw, qb, kw, M, bias);
    hipLaunchKernelGGL(k_w2,   dim3(64),  dim3(256), 0, stream, vw, W2);
    hipLaunchKernelGGL(k_qk,   dim3(128), dim3(256), 0, stream, qfeat, M, bias, qk_all);
    if (tier == 1){
        hipLaunchKernelGGL(k_padT,      dim3(5000), dim3(256), 0, stream, feat, featT);
        hipLaunchKernelGGL(k_attn_feat, dim3(4096), dim3(256), 0, stream, featT, qk_all, proj, g);
    } else {
        hipLaunchKernelGGL(k_attn_direct, dim3(4096), dim3(256), 0, stream, feat, qk_all, proj, g);
    }
    hipLaunchKernelGGL(k_out,  dim3(128), dim3(256), 0, stream, g, W2, qfeat, vb, out);
}